// Round 2
// baseline (284.160 us; speedup 1.0000x reference)
//
#include <hip/hip_runtime.h>

#define T_SEQ 2048
#define DM 1024
#define NH 16
#define DKH 64
#define NBATCH 4
#define MROWS (NBATCH*T_SEQ)   // 8192

typedef __attribute__((ext_vector_type(8))) short bf16x8;
typedef __attribute__((ext_vector_type(4))) short bf16x4;
typedef __attribute__((ext_vector_type(4))) float f32x4;
typedef __attribute__((ext_vector_type(4))) unsigned short u16x4;

#define NEG_INF (-__builtin_inff())

static __device__ __forceinline__ unsigned short f2bf(float f){
  union { float f; unsigned u; } v; v.f = f;
  unsigned r = v.u + 0x7fffu + ((v.u >> 16) & 1u);
  return (unsigned short)(r >> 16);
}

static __device__ __forceinline__ void gload_lds16(const void* g, void* l){
  __builtin_amdgcn_global_load_lds(
      (const __attribute__((address_space(1))) void*)g,
      (__attribute__((address_space(3))) void*)l, 16, 0, 0);
}

// ---------------- convert H (fp32 -> bf16) ----------------
__global__ void convh(const float4* __restrict__ in, u16x4* __restrict__ out, int n4){
  for (int i = blockIdx.x*blockDim.x + threadIdx.x; i < n4; i += gridDim.x*blockDim.x){
    float4 v = in[i];
    u16x4 o;
    o[0] = f2bf(v.x); o[1] = f2bf(v.y); o[2] = f2bf(v.z); o[3] = f2bf(v.w);
    out[i] = o;
  }
}

// ------------- convert + transpose weights (fp32 [k][n] -> bf16 [n][k]) -------------
__global__ void convw(const float* __restrict__ W0, const float* __restrict__ W1,
                      const float* __restrict__ W2, const float* __restrict__ W3,
                      unsigned short* __restrict__ O0, unsigned short* __restrict__ O1,
                      unsigned short* __restrict__ O2, unsigned short* __restrict__ O3)
{
  const float* W = (blockIdx.z==0)?W0:(blockIdx.z==1)?W1:(blockIdx.z==2)?W2:W3;
  unsigned short* O = (blockIdx.z==0)?O0:(blockIdx.z==1)?O1:(blockIdx.z==2)?O2:O3;
  __shared__ float t[32][33];
  const int nx = blockIdx.x*32, kx = blockIdx.y*32;
  const int tx = threadIdx.x, ty = threadIdx.y;
  #pragma unroll
  for (int i = 0; i < 4; ++i)
    t[ty + i*8][tx] = W[(size_t)(kx + ty + i*8)*DM + nx + tx];
  __syncthreads();
  #pragma unroll
  for (int i = 0; i < 4; ++i)
    O[(size_t)(nx + ty + i*8)*DM + kx + tx] = f2bf(t[tx][ty + i*8]);
}

// ---------------- GEMM: C[M][N] = A[M][K](bf16) * Bt[N][K](bf16)^T ----------------
// 128x128 tile, BK=64, 4 waves (2x2), 16x16x32 bf16 MFMA, global_load_lds staging,
// XOR-swizzled LDS ((row&7) chunk-XOR within 128B rows) for conflict-free ds_read_b128.
template<bool F32OUT>
__global__ __launch_bounds__(256) void gemm_bt(const unsigned short* __restrict__ A,
                                               const unsigned short* __restrict__ Bt,
                                               void* __restrict__ Cp,
                                               int M, int N, int K)
{
  __shared__ __attribute__((aligned(16))) unsigned short a_lds[128*64];
  __shared__ __attribute__((aligned(16))) unsigned short b_lds[128*64];
  const int tid = threadIdx.x;
  const int w = tid >> 6, l = tid & 63;
  const int g = l >> 4, lr = l & 15;
  const int wr = w >> 1, wc = w & 1;
  const int m0 = blockIdx.x * 128, n0 = blockIdx.y * 128;
  f32x4 acc[4][4] = {};
  const int nk = K >> 6;
  for (int ks = 0; ks < nk; ++ks){
    __syncthreads();
    const int k0 = ks << 6;
    #pragma unroll
    for (int i = 0; i < 4; ++i){
      int c = (w*4 + i)*64 + l;           // 0..1023, 16B chunks
      int row = c >> 3;
      int gc = (c & 7) ^ (row & 7);       // pre-swizzled global source (m173 pattern)
      gload_lds16(A + (size_t)(m0 + row)*K + (k0 + gc*8), &a_lds[c*8]);
    }
    #pragma unroll
    for (int i = 0; i < 4; ++i){
      int c = (w*4 + i)*64 + l;
      int row = c >> 3;
      int gc = (c & 7) ^ (row & 7);
      gload_lds16(Bt + (size_t)(n0 + row)*K + (k0 + gc*8), &b_lds[c*8]);
    }
    __syncthreads();
    #pragma unroll
    for (int kc = 0; kc < 2; ++kc){
      bf16x8 af[4], bf_[4];
      #pragma unroll
      for (int mt = 0; mt < 4; ++mt){
        int row = wr*64 + mt*16 + lr;
        int off = row*128 + ((kc*64 + g*16) ^ ((row & 7) << 4));
        af[mt] = *(const bf16x8*)((const char*)a_lds + off);
      }
      #pragma unroll
      for (int nt = 0; nt < 4; ++nt){
        int row = wc*64 + nt*16 + lr;
        int off = row*128 + ((kc*64 + g*16) ^ ((row & 7) << 4));
        bf_[nt] = *(const bf16x8*)((const char*)b_lds + off);
      }
      #pragma unroll
      for (int mt = 0; mt < 4; ++mt)
        #pragma unroll
        for (int nt = 0; nt < 4; ++nt)
          acc[mt][nt] = __builtin_amdgcn_mfma_f32_16x16x32_bf16(af[mt], bf_[nt], acc[mt][nt], 0, 0, 0);
    }
  }
  #pragma unroll
  for (int mt = 0; mt < 4; ++mt){
    #pragma unroll
    for (int nt = 0; nt < 4; ++nt){
      const int col = n0 + wc*64 + nt*16 + lr;
      #pragma unroll
      for (int r = 0; r < 4; ++r){
        const int row = m0 + wr*64 + mt*16 + 4*g + r;   // C/D: col=lane&15, row=(lane>>4)*4+r (m89)
        if (F32OUT) ((float*)Cp)[(size_t)row*N + col] = acc[mt][nt][r];
        else ((unsigned short*)Cp)[(size_t)row*N + col] = f2bf(acc[mt][nt][r]);
      }
    }
  }
}

// ---------------- causal flash attention ----------------
// Grid: (32 q-tiles, 64 bh). Block: 4 waves, each owns 16 q-rows (QBLK=64), KVBLK=64.
// Swapped QK^T: S^T = mfma(K_frag, Q_frag) -> lane holds S[q=lane&15][kv=16kc+4g+r]
//   -> softmax stats lane-local in q, row-reduce = shfl_xor(16,32).
// PV: O^T = V^T @ P^T via mfma_16x16x16bf16_1k. THIS ROUND: no tr_read — V is
// explicitly transposed into LDS vt[dk][kv] (reg-staged, scalar ds_write_b16),
// A-fragments are plain aligned ds_read_b64 C-derefs. B=P^T directly from the
// S^T register layout (zero cross-lane movement).
__global__ __launch_bounds__(256) void attn_kernel(const unsigned short* __restrict__ Qg,
                                                   const unsigned short* __restrict__ Kg,
                                                   const unsigned short* __restrict__ Vg,
                                                   unsigned short* __restrict__ Og)
{
  __shared__ __attribute__((aligned(16))) unsigned short k_lds[64*64];
  __shared__ __attribute__((aligned(16))) unsigned short vt_lds[64][68]; // [dk][kv], pad->8B-aligned rows, 2-way-free banks
  const int tid = threadIdx.x;
  const int w = tid >> 6, l = tid & 63;
  const int g = l >> 4, lr = l & 15;
  const int qblk = blockIdx.x, bh = blockIdx.y;
  const int b = bh >> 4, h = bh & 15;
  const int q0 = qblk * 64;
  const int qg = q0 + w*16 + lr;                       // this lane's q row
  const size_t rowQ = (size_t)(b*T_SEQ + qg)*DM + h*DKH;
  bf16x8 qf[2];
  qf[0] = *(const bf16x8*)(Qg + rowQ + g*8);
  qf[1] = *(const bf16x8*)(Qg + rowQ + 32 + g*8);
  float m_run = NEG_INF, l_run = 0.f;
  f32x4 acc[4] = {};                                    // acc[mt]: O^T[dk=16mt+4g+r][q=lr]
  const int ntiles = qblk + 1;
  const size_t baseKV = (size_t)(b*T_SEQ)*DM + h*DKH;

  for (int jt = 0; jt < ntiles; ++jt){
    const int j0 = jt * 64;
    __syncthreads();                                    // prior compute done before overwrite
    #pragma unroll
    for (int i = 0; i < 2; ++i){                        // K tile, swizzled via global-src pre-swizzle
      int c = (w*2 + i)*64 + l;                         // 0..511 16B chunks
      int row = c >> 3;
      int gc = (c & 7) ^ (row & 7);
      gload_lds16(Kg + baseKV + (size_t)(j0 + row)*DM + gc*8, &k_lds[c*8]);
    }
    #pragma unroll
    for (int i = 0; i < 2; ++i){                        // V: reg-stage + explicit transpose into vt[dk][kv]
      int c = tid + i*256;                              // 0..511 chunks of 8 bf16
      int kv = c >> 3, seg = c & 7;
      bf16x8 v = *(const bf16x8*)(Vg + baseKV + (size_t)(j0 + kv)*DM + seg*8);
      #pragma unroll
      for (int e = 0; e < 8; ++e)
        vt_lds[seg*8 + e][kv] = (unsigned short)v[e];
    }
    __syncthreads();                                    // drains vmcnt (K gload, V loads) + lgkmcnt (vt writes)

    // QK^T (swapped): S^T tiles, kv=16 each
    f32x4 s[4];
    #pragma unroll
    for (int kc = 0; kc < 4; ++kc){
      f32x4 z = {};
      #pragma unroll
      for (int c2 = 0; c2 < 2; ++c2){
        int row = kc*16 + lr;
        int off = row*128 + ((c2*64 + g*16) ^ ((row & 7) << 4));
        bf16x8 kf = *(const bf16x8*)((const char*)k_lds + off);
        z = __builtin_amdgcn_mfma_f32_16x16x32_bf16(kf, qf[c2], z, 0, 0, 0);
      }
      s[kc] = z;
    }
    // scale + causal mask + tile max
    float p[4][4];
    float tm = NEG_INF;
    #pragma unroll
    for (int kc = 0; kc < 4; ++kc)
      #pragma unroll
      for (int r = 0; r < 4; ++r){
        int kvg = j0 + kc*16 + 4*g + r;
        float v = s[kc][r] * 0.125f;                    // 1/sqrt(64)
        v = (kvg <= qg) ? v : NEG_INF;
        p[kc][r] = v;
        tm = fmaxf(tm, v);
      }
    tm = fmaxf(tm, __shfl_xor(tm, 16));
    tm = fmaxf(tm, __shfl_xor(tm, 32));
    const float m_new = fmaxf(m_run, tm);
    const float fac = __expf(m_run - m_new);            // first tile: exp(-inf)=0
    float ps = 0.f;
    #pragma unroll
    for (int kc = 0; kc < 4; ++kc)
      #pragma unroll
      for (int r = 0; r < 4; ++r){
        float e = __expf(p[kc][r] - m_new);
        p[kc][r] = e;
        ps += e;
      }
    ps += __shfl_xor(ps, 16);
    ps += __shfl_xor(ps, 32);
    l_run = l_run * fac + ps;
    m_run = m_new;
    #pragma unroll
    for (int mt = 0; mt < 4; ++mt){
      acc[mt][0] *= fac; acc[mt][1] *= fac; acc[mt][2] *= fac; acc[mt][3] *= fac;
    }
    // pack P^T fragments (B-operand of 16x16x16: B[k=4g+i][n=lr] = p[kc][i] -- direct)
    bf16x4 pb[4];
    #pragma unroll
    for (int kc = 0; kc < 4; ++kc){
      bf16x4 t;
      t[0] = (short)f2bf(p[kc][0]); t[1] = (short)f2bf(p[kc][1]);
      t[2] = (short)f2bf(p[kc][2]); t[3] = (short)f2bf(p[kc][3]);
      pb[kc] = t;
    }
    // PV: A-frag = V^T[dk=mt*16+lr][kv=kc*16+4g..+3] = 4 contiguous shorts of vt_lds (8B-aligned)
    #pragma unroll
    for (int mt = 0; mt < 4; ++mt){
      #pragma unroll
      for (int kc = 0; kc < 4; ++kc){
        bf16x4 vf = *(const bf16x4*)&vt_lds[mt*16 + lr][kc*16 + 4*g];
        acc[mt] = __builtin_amdgcn_mfma_f32_16x16x16bf16_1k(vf, pb[kc], acc[mt], 0, 0, 0);
      }
    }
  }
  // epilogue: normalize, pack pairs, store bf16
  const float inv = 1.f / l_run;
  const size_t rowO = (size_t)(b*T_SEQ + qg)*DM + h*DKH;
  #pragma unroll
  for (int mt = 0; mt < 4; ++mt){
    unsigned u0 = (unsigned)f2bf(acc[mt][0]*inv) | ((unsigned)f2bf(acc[mt][1]*inv) << 16);
    unsigned u1 = (unsigned)f2bf(acc[mt][2]*inv) | ((unsigned)f2bf(acc[mt][3]*inv) << 16);
    *(unsigned*)(Og + rowO + mt*16 + 4*g)     = u0;
    *(unsigned*)(Og + rowO + mt*16 + 4*g + 2) = u1;
  }
}

// ---------------- launch ----------------
extern "C" void kernel_launch(void* const* d_in, const int* in_sizes, int n_in,
                              void* d_out, int out_size, void* d_ws, size_t ws_size,
                              hipStream_t stream)
{
  (void)in_sizes; (void)n_in; (void)out_size; (void)ws_size;
  const float* H  = (const float*)d_in[0];
  const float* Wq = (const float*)d_in[1];
  const float* Wk = (const float*)d_in[2];
  const float* Wv = (const float*)d_in[3];
  const float* Wo = (const float*)d_in[4];
  char* ws = (char*)d_ws;
  // ws layout (bytes): Hb 16MB | Wq/Wk/Wv/Wo^T bf16 2MB each | Q,K,V 16MB each | Ab 16MB = 88MB
  unsigned short* Hb  = (unsigned short*)(ws);
  unsigned short* Wqt = (unsigned short*)(ws + 16777216);
  unsigned short* Wkt = (unsigned short*)(ws + 18874368);
  unsigned short* Wvt = (unsigned short*)(ws + 20971520);
  unsigned short* Wot = (unsigned short*)(ws + 23068672);
  unsigned short* Qb  = (unsigned short*)(ws + 25165824);
  unsigned short* Kb  = (unsigned short*)(ws + 41943040);
  unsigned short* Vb  = (unsigned short*)(ws + 58720256);
  unsigned short* Ab  = (unsigned short*)(ws + 75497472);

  convh<<<2048, 256, 0, stream>>>((const float4*)H, (u16x4*)Hb, MROWS*DM/4);
  convw<<<dim3(32,32,4), dim3(32,8), 0, stream>>>(Wq, Wk, Wv, Wo, Wqt, Wkt, Wvt, Wot);
  gemm_bt<false><<<dim3(64,8), 256, 0, stream>>>(Hb, Wqt, Qb, MROWS, DM, DM);
  gemm_bt<false><<<dim3(64,8), 256, 0, stream>>>(Hb, Wkt, Kb, MROWS, DM, DM);
  gemm_bt<false><<<dim3(64,8), 256, 0, stream>>>(Hb, Wvt, Vb, MROWS, DM, DM);
  attn_kernel<<<dim3(32,64), 256, 0, stream>>>(Qb, Kb, Vb, Ab);
  gemm_bt<true><<<dim3(64,8), 256, 0, stream>>>(Ab, Wot, d_out, MROWS, DM, DM);
}

// Round 3
// 266.184 us; speedup vs baseline: 1.0675x; 1.0675x over previous
//
#include <hip/hip_runtime.h>

#define T_SEQ 2048
#define DM 1024
#define NH 16
#define DKH 64
#define NBATCH 4
#define MROWS (NBATCH*T_SEQ)   // 8192

typedef __attribute__((ext_vector_type(8))) short bf16x8;
typedef __attribute__((ext_vector_type(4))) short bf16x4;
typedef __attribute__((ext_vector_type(4))) float f32x4;
typedef __attribute__((ext_vector_type(4))) unsigned short u16x4;

#define NEG_INF (-__builtin_inff())

static __device__ __forceinline__ unsigned short f2bf(float f){
  union { float f; unsigned u; } v; v.f = f;
  unsigned r = v.u + 0x7fffu + ((v.u >> 16) & 1u);
  return (unsigned short)(r >> 16);
}

static __device__ __forceinline__ void gload_lds16(const void* g, void* l){
  __builtin_amdgcn_global_load_lds(
      (const __attribute__((address_space(1))) void*)g,
      (__attribute__((address_space(3))) void*)l, 16, 0, 0);
}

// ---------------- convert H (fp32 -> bf16) ----------------
__global__ void convh(const float4* __restrict__ in, u16x4* __restrict__ out, int n4){
  for (int i = blockIdx.x*blockDim.x + threadIdx.x; i < n4; i += gridDim.x*blockDim.x){
    float4 v = in[i];
    u16x4 o;
    o[0] = f2bf(v.x); o[1] = f2bf(v.y); o[2] = f2bf(v.z); o[3] = f2bf(v.w);
    out[i] = o;
  }
}

// ------------- convert + transpose weights (fp32 [k][n] -> bf16 [n][k]) -------------
__global__ void convw(const float* __restrict__ W0, const float* __restrict__ W1,
                      const float* __restrict__ W2, const float* __restrict__ W3,
                      unsigned short* __restrict__ O0, unsigned short* __restrict__ O1,
                      unsigned short* __restrict__ O2, unsigned short* __restrict__ O3)
{
  const float* W = (blockIdx.z==0)?W0:(blockIdx.z==1)?W1:(blockIdx.z==2)?W2:W3;
  unsigned short* O = (blockIdx.z==0)?O0:(blockIdx.z==1)?O1:(blockIdx.z==2)?O2:O3;
  __shared__ float t[32][33];
  const int nx = blockIdx.x*32, kx = blockIdx.y*32;
  const int tx = threadIdx.x, ty = threadIdx.y;
  #pragma unroll
  for (int i = 0; i < 4; ++i)
    t[ty + i*8][tx] = W[(size_t)(kx + ty + i*8)*DM + nx + tx];
  __syncthreads();
  #pragma unroll
  for (int i = 0; i < 4; ++i)
    O[(size_t)(nx + ty + i*8)*DM + kx + tx] = f2bf(t[tx][ty + i*8]);
}

// ---------------- GEMM: C[M][N] = A[M][K](bf16) * Bt[N][K](bf16)^T ----------------
// 128x128 tile, BK=64, 4 waves (2x2), 16x16x32 bf16 MFMA, global_load_lds staging,
// XOR-swizzled LDS ((row&7) chunk-XOR within 128B rows) for conflict-free ds_read_b128.
template<bool F32OUT>
__global__ __launch_bounds__(256) void gemm_bt(const unsigned short* __restrict__ A,
                                               const unsigned short* __restrict__ Bt,
                                               void* __restrict__ Cp,
                                               int M, int N, int K)
{
  __shared__ __attribute__((aligned(16))) unsigned short a_lds[128*64];
  __shared__ __attribute__((aligned(16))) unsigned short b_lds[128*64];
  const int tid = threadIdx.x;
  const int w = tid >> 6, l = tid & 63;
  const int g = l >> 4, lr = l & 15;
  const int wr = w >> 1, wc = w & 1;
  const int m0 = blockIdx.x * 128, n0 = blockIdx.y * 128;
  f32x4 acc[4][4] = {};
  const int nk = K >> 6;
  for (int ks = 0; ks < nk; ++ks){
    __syncthreads();
    const int k0 = ks << 6;
    #pragma unroll
    for (int i = 0; i < 4; ++i){
      int c = (w*4 + i)*64 + l;           // 0..1023, 16B chunks
      int row = c >> 3;
      int gc = (c & 7) ^ (row & 7);       // pre-swizzled global source (m173 pattern)
      gload_lds16(A + (size_t)(m0 + row)*K + (k0 + gc*8), &a_lds[c*8]);
    }
    #pragma unroll
    for (int i = 0; i < 4; ++i){
      int c = (w*4 + i)*64 + l;
      int row = c >> 3;
      int gc = (c & 7) ^ (row & 7);
      gload_lds16(Bt + (size_t)(n0 + row)*K + (k0 + gc*8), &b_lds[c*8]);
    }
    __syncthreads();
    #pragma unroll
    for (int kc = 0; kc < 2; ++kc){
      bf16x8 af[4], bf_[4];
      #pragma unroll
      for (int mt = 0; mt < 4; ++mt){
        int row = wr*64 + mt*16 + lr;
        int off = row*128 + ((kc*64 + g*16) ^ ((row & 7) << 4));
        af[mt] = *(const bf16x8*)((const char*)a_lds + off);
      }
      #pragma unroll
      for (int nt = 0; nt < 4; ++nt){
        int row = wc*64 + nt*16 + lr;
        int off = row*128 + ((kc*64 + g*16) ^ ((row & 7) << 4));
        bf_[nt] = *(const bf16x8*)((const char*)b_lds + off);
      }
      #pragma unroll
      for (int mt = 0; mt < 4; ++mt)
        #pragma unroll
        for (int nt = 0; nt < 4; ++nt)
          acc[mt][nt] = __builtin_amdgcn_mfma_f32_16x16x32_bf16(af[mt], bf_[nt], acc[mt][nt], 0, 0, 0);
    }
  }
  #pragma unroll
  for (int mt = 0; mt < 4; ++mt){
    #pragma unroll
    for (int nt = 0; nt < 4; ++nt){
      const int col = n0 + wc*64 + nt*16 + lr;
      #pragma unroll
      for (int r = 0; r < 4; ++r){
        const int row = m0 + wr*64 + mt*16 + 4*g + r;   // C/D: col=lane&15, row=(lane>>4)*4+r (m89)
        if (F32OUT) ((float*)Cp)[(size_t)row*N + col] = acc[mt][nt][r];
        else ((unsigned short*)Cp)[(size_t)row*N + col] = f2bf(acc[mt][nt][r]);
      }
    }
  }
}

// ---------------- causal flash attention ----------------
// Grid: (32 q-tiles, 64 bh). Block: 4 waves, each owns 16 q-rows (QBLK=64), KVBLK=64.
// Swapped QK^T: S^T = mfma(K_frag, Q_frag) -> lane holds S[q=lane&15][kv=16kc+4g+r]
//   -> softmax stats lane-local in q, row-reduce = shfl_xor(16,32).
// PV: O^T = V^T @ P^T via mfma_16x16x16bf16_1k. V^T comes PRE-TRANSPOSED from a
// GEMM (Vt[n=1024][t=8192]); staged with swizzled global_load_lds like K, and
// A-fragments are plain swizzled 8B LDS reads. B=P^T directly from the S^T
// register layout (zero cross-lane movement).
// K/V double-buffered (2-phase): STAGE(jt+1) issued before COMPUTE(jt), one
// barrier (implicit vmcnt drain) per tile.
__global__ __launch_bounds__(256) void attn_kernel(const unsigned short* __restrict__ Qg,
                                                   const unsigned short* __restrict__ Kg,
                                                   const unsigned short* __restrict__ Vt,
                                                   unsigned short* __restrict__ Og)
{
  __shared__ __attribute__((aligned(16))) unsigned short k_lds[2][64*64];
  __shared__ __attribute__((aligned(16))) unsigned short v_lds[2][64*64];
  const int tid = threadIdx.x;
  const int w = tid >> 6, l = tid & 63;
  const int g = l >> 4, lr = l & 15;
  const int qblk = blockIdx.x, bh = blockIdx.y;
  const int b = bh >> 4, h = bh & 15;
  const int q0 = qblk * 64;
  const int qg = q0 + w*16 + lr;                       // this lane's q row
  const size_t rowQ = (size_t)(b*T_SEQ + qg)*DM + h*DKH;
  bf16x8 qf[2];
  qf[0] = *(const bf16x8*)(Qg + rowQ + g*8);
  qf[1] = *(const bf16x8*)(Qg + rowQ + 32 + g*8);
  float m_run = NEG_INF, l_run = 0.f;
  f32x4 acc[4] = {};                                    // acc[mt]: O^T[dk=16mt+4g+r][q=lr]
  const int ntiles = qblk + 1;
  const size_t baseK = (size_t)(b*T_SEQ)*DM + h*DKH;            // K rows [t][n]
  const size_t baseV = (size_t)(h*DKH)*MROWS + (size_t)b*T_SEQ; // Vt rows [n][t]

  // per-thread staging geometry (loop-invariant)
  const int c0 = (w*2 + 0)*64 + l, c1 = (w*2 + 1)*64 + l;       // 16B chunk ids 0..511
  const int r0 = c0 >> 3, gc0 = (c0 & 7) ^ (r0 & 7);
  const int r1 = c1 >> 3, gc1 = (c1 & 7) ^ (r1 & 7);

  auto STAGE = [&](int jt, int buf){
    const int j0 = jt * 64;
    gload_lds16(Kg + baseK + (size_t)(j0 + r0)*DM + gc0*8, &k_lds[buf][c0*8]);
    gload_lds16(Kg + baseK + (size_t)(j0 + r1)*DM + gc1*8, &k_lds[buf][c1*8]);
    gload_lds16(Vt + baseV + (size_t)r0*MROWS + j0 + gc0*8, &v_lds[buf][c0*8]);
    gload_lds16(Vt + baseV + (size_t)r1*MROWS + j0 + gc1*8, &v_lds[buf][c1*8]);
  };

  STAGE(0, 0);
  __syncthreads();                                      // drains vmcnt -> buf0 ready

  for (int jt = 0; jt < ntiles; ++jt){
    const int cur = jt & 1;
    if (jt + 1 < ntiles) STAGE(jt + 1, cur ^ 1);        // prefetch next tile (hidden under compute)
    const int j0 = jt * 64;

    // QK^T (swapped): S^T tiles, kv=16 each
    f32x4 s[4];
    #pragma unroll
    for (int kc = 0; kc < 4; ++kc){
      f32x4 z = {};
      #pragma unroll
      for (int c2 = 0; c2 < 2; ++c2){
        int row = kc*16 + lr;
        int off = row*128 + ((c2*64 + g*16) ^ ((row & 7) << 4));
        bf16x8 kf = *(const bf16x8*)((const char*)k_lds[cur] + off);
        z = __builtin_amdgcn_mfma_f32_16x16x32_bf16(kf, qf[c2], z, 0, 0, 0);
      }
      s[kc] = z;
    }
    // scale + causal mask + tile max
    float p[4][4];
    float tm = NEG_INF;
    #pragma unroll
    for (int kc = 0; kc < 4; ++kc)
      #pragma unroll
      for (int r = 0; r < 4; ++r){
        int kvg = j0 + kc*16 + 4*g + r;
        float v = s[kc][r] * 0.125f;                    // 1/sqrt(64)
        v = (kvg <= qg) ? v : NEG_INF;
        p[kc][r] = v;
        tm = fmaxf(tm, v);
      }
    tm = fmaxf(tm, __shfl_xor(tm, 16));
    tm = fmaxf(tm, __shfl_xor(tm, 32));
    const float m_new = fmaxf(m_run, tm);
    const float fac = __expf(m_run - m_new);            // first tile: exp(-inf)=0
    float ps = 0.f;
    #pragma unroll
    for (int kc = 0; kc < 4; ++kc)
      #pragma unroll
      for (int r = 0; r < 4; ++r){
        float e = __expf(p[kc][r] - m_new);
        p[kc][r] = e;
        ps += e;
      }
    ps += __shfl_xor(ps, 16);
    ps += __shfl_xor(ps, 32);
    l_run = l_run * fac + ps;
    m_run = m_new;
    #pragma unroll
    for (int mt = 0; mt < 4; ++mt){
      acc[mt][0] *= fac; acc[mt][1] *= fac; acc[mt][2] *= fac; acc[mt][3] *= fac;
    }
    // pack P^T fragments (B-operand of 16x16x16: B[k=4g+i][n=lr] = p[kc][i] -- direct)
    bf16x4 pb[4];
    #pragma unroll
    for (int kc = 0; kc < 4; ++kc){
      bf16x4 t;
      t[0] = (short)f2bf(p[kc][0]); t[1] = (short)f2bf(p[kc][1]);
      t[2] = (short)f2bf(p[kc][2]); t[3] = (short)f2bf(p[kc][3]);
      pb[kc] = t;
    }
    // PV: A-frag = V^T[dk=mt*16+lr][kv=kc*16+4g..+3], swizzled 8B read from v_lds
    #pragma unroll
    for (int mt = 0; mt < 4; ++mt){
      const int vrow = mt*16 + lr;
      #pragma unroll
      for (int kc = 0; kc < 4; ++kc){
        const int voff = vrow*128 + ((((kc<<1) + (g>>1)) ^ (vrow & 7)) << 4) + ((g & 1) << 3);
        bf16x4 vf = *(const bf16x4*)((const char*)v_lds[cur] + voff);
        acc[mt] = __builtin_amdgcn_mfma_f32_16x16x16bf16_1k(vf, pb[kc], acc[mt], 0, 0, 0);
      }
    }
    __syncthreads();                                    // all waves done with buf[cur]; prefetch drained
  }
  // epilogue: normalize, pack pairs, store bf16
  const float inv = 1.f / l_run;
  const size_t rowO = (size_t)(b*T_SEQ + qg)*DM + h*DKH;
  #pragma unroll
  for (int mt = 0; mt < 4; ++mt){
    unsigned u0 = (unsigned)f2bf(acc[mt][0]*inv) | ((unsigned)f2bf(acc[mt][1]*inv) << 16);
    unsigned u1 = (unsigned)f2bf(acc[mt][2]*inv) | ((unsigned)f2bf(acc[mt][3]*inv) << 16);
    *(unsigned*)(Og + rowO + mt*16 + 4*g)     = u0;
    *(unsigned*)(Og + rowO + mt*16 + 4*g + 2) = u1;
  }
}

// ---------------- launch ----------------
extern "C" void kernel_launch(void* const* d_in, const int* in_sizes, int n_in,
                              void* d_out, int out_size, void* d_ws, size_t ws_size,
                              hipStream_t stream)
{
  (void)in_sizes; (void)n_in; (void)out_size; (void)ws_size;
  const float* H  = (const float*)d_in[0];
  const float* Wq = (const float*)d_in[1];
  const float* Wk = (const float*)d_in[2];
  const float* Wv = (const float*)d_in[3];
  const float* Wo = (const float*)d_in[4];
  char* ws = (char*)d_ws;
  // ws layout (bytes): Hb 16MB | Wq/Wk/Wv/Wo^T bf16 2MB each | Q,K 16MB each | Vt 16MB | Ab 16MB = 88MB
  unsigned short* Hb  = (unsigned short*)(ws);
  unsigned short* Wqt = (unsigned short*)(ws + 16777216);
  unsigned short* Wkt = (unsigned short*)(ws + 18874368);
  unsigned short* Wvt = (unsigned short*)(ws + 20971520);
  unsigned short* Wot = (unsigned short*)(ws + 23068672);
  unsigned short* Qb  = (unsigned short*)(ws + 25165824);
  unsigned short* Kb  = (unsigned short*)(ws + 41943040);
  unsigned short* Vtb = (unsigned short*)(ws + 58720256);
  unsigned short* Ab  = (unsigned short*)(ws + 75497472);

  convh<<<2048, 256, 0, stream>>>((const float4*)H, (u16x4*)Hb, MROWS*DM/4);
  convw<<<dim3(32,32,4), dim3(32,8), 0, stream>>>(Wq, Wk, Wv, Wo, Wqt, Wkt, Wvt, Wot);
  gemm_bt<false><<<dim3(64,8), 256, 0, stream>>>(Hb, Wqt, Qb, MROWS, DM, DM);
  gemm_bt<false><<<dim3(64,8), 256, 0, stream>>>(Hb, Wkt, Kb, MROWS, DM, DM);
  // V^T = (H Wv)^T computed directly: C[n][t] = sum_k Wvt[n][k] * Hb[t][k]
  gemm_bt<false><<<dim3(8,64), 256, 0, stream>>>(Wvt, Hb, Vtb, DM, MROWS, DM);
  attn_kernel<<<dim3(32,64), 256, 0, stream>>>(Qb, Kb, Vtb, Ab);
  gemm_bt<true><<<dim3(64,8), 256, 0, stream>>>(Ab, Wot, d_out, MROWS, DM, DM);
}

// Round 4
// 215.404 us; speedup vs baseline: 1.3192x; 1.2357x over previous
//
#include <hip/hip_runtime.h>

#define T_SEQ 2048
#define DM 1024
#define NH 16
#define DKH 64
#define NBATCH 4
#define MROWS (NBATCH*T_SEQ)   // 8192

typedef __attribute__((ext_vector_type(8))) short bf16x8;
typedef __attribute__((ext_vector_type(4))) short bf16x4;
typedef __attribute__((ext_vector_type(4))) float f32x4;
typedef __attribute__((ext_vector_type(4))) unsigned short u16x4;

#define NEG_INF (-__builtin_inff())

static __device__ __forceinline__ unsigned short f2bf(float f){
  union { float f; unsigned u; } v; v.f = f;
  unsigned r = v.u + 0x7fffu + ((v.u >> 16) & 1u);
  return (unsigned short)(r >> 16);
}

static __device__ __forceinline__ void gload_lds16(const void* g, void* l){
  __builtin_amdgcn_global_load_lds(
      (const __attribute__((address_space(1))) void*)g,
      (__attribute__((address_space(3))) void*)l, 16, 0, 0);
}

// ---------------- convert H (fp32 -> bf16) ----------------
__global__ void convh(const float4* __restrict__ in, u16x4* __restrict__ out, int n4){
  for (int i = blockIdx.x*blockDim.x + threadIdx.x; i < n4; i += gridDim.x*blockDim.x){
    float4 v = in[i];
    u16x4 o;
    o[0] = f2bf(v.x); o[1] = f2bf(v.y); o[2] = f2bf(v.z); o[3] = f2bf(v.w);
    out[i] = o;
  }
}

// ------------- convert + transpose weights (fp32 [k][n] -> bf16 [n][k]) -------------
__global__ void convw(const float* __restrict__ W0, const float* __restrict__ W1,
                      const float* __restrict__ W2, const float* __restrict__ W3,
                      unsigned short* __restrict__ O0, unsigned short* __restrict__ O1,
                      unsigned short* __restrict__ O2, unsigned short* __restrict__ O3)
{
  const float* W = (blockIdx.z==0)?W0:(blockIdx.z==1)?W1:(blockIdx.z==2)?W2:W3;
  unsigned short* O = (blockIdx.z==0)?O0:(blockIdx.z==1)?O1:(blockIdx.z==2)?O2:O3;
  __shared__ float t[32][33];
  const int nx = blockIdx.x*32, kx = blockIdx.y*32;
  const int tx = threadIdx.x, ty = threadIdx.y;
  #pragma unroll
  for (int i = 0; i < 4; ++i)
    t[ty + i*8][tx] = W[(size_t)(kx + ty + i*8)*DM + nx + tx];
  __syncthreads();
  #pragma unroll
  for (int i = 0; i < 4; ++i)
    O[(size_t)(nx + ty + i*8)*DM + kx + tx] = f2bf(t[tx][ty + i*8]);
}

// ---------------- GEMM: C[M][N] = oscale * A[M][K](bf16) * Bt[N][K](bf16)^T ----------------
// 128x128 tile, BK=64, 4 waves (2x2), 16x16x32 bf16 MFMA, global_load_lds staging,
// XOR-swizzled LDS ((row&7) chunk-XOR within 128B rows) for conflict-free ds_read_b128.
template<bool F32OUT>
__global__ __launch_bounds__(256) void gemm_bt(const unsigned short* __restrict__ A,
                                               const unsigned short* __restrict__ Bt,
                                               void* __restrict__ Cp,
                                               int M, int N, int K, float oscale)
{
  __shared__ __attribute__((aligned(16))) unsigned short a_lds[128*64];
  __shared__ __attribute__((aligned(16))) unsigned short b_lds[128*64];
  const int tid = threadIdx.x;
  const int w = tid >> 6, l = tid & 63;
  const int g = l >> 4, lr = l & 15;
  const int wr = w >> 1, wc = w & 1;
  const int m0 = blockIdx.x * 128, n0 = blockIdx.y * 128;
  f32x4 acc[4][4] = {};
  const int nk = K >> 6;
  for (int ks = 0; ks < nk; ++ks){
    __syncthreads();
    const int k0 = ks << 6;
    #pragma unroll
    for (int i = 0; i < 4; ++i){
      int c = (w*4 + i)*64 + l;           // 0..1023, 16B chunks
      int row = c >> 3;
      int gc = (c & 7) ^ (row & 7);       // pre-swizzled global source (m173 pattern)
      gload_lds16(A + (size_t)(m0 + row)*K + (k0 + gc*8), &a_lds[c*8]);
    }
    #pragma unroll
    for (int i = 0; i < 4; ++i){
      int c = (w*4 + i)*64 + l;
      int row = c >> 3;
      int gc = (c & 7) ^ (row & 7);
      gload_lds16(Bt + (size_t)(n0 + row)*K + (k0 + gc*8), &b_lds[c*8]);
    }
    __syncthreads();
    #pragma unroll
    for (int kc = 0; kc < 2; ++kc){
      bf16x8 af[4], bf_[4];
      #pragma unroll
      for (int mt = 0; mt < 4; ++mt){
        int row = wr*64 + mt*16 + lr;
        int off = row*128 + ((kc*64 + g*16) ^ ((row & 7) << 4));
        af[mt] = *(const bf16x8*)((const char*)a_lds + off);
      }
      #pragma unroll
      for (int nt = 0; nt < 4; ++nt){
        int row = wc*64 + nt*16 + lr;
        int off = row*128 + ((kc*64 + g*16) ^ ((row & 7) << 4));
        bf_[nt] = *(const bf16x8*)((const char*)b_lds + off);
      }
      #pragma unroll
      for (int mt = 0; mt < 4; ++mt)
        #pragma unroll
        for (int nt = 0; nt < 4; ++nt)
          acc[mt][nt] = __builtin_amdgcn_mfma_f32_16x16x32_bf16(af[mt], bf_[nt], acc[mt][nt], 0, 0, 0);
    }
  }
  #pragma unroll
  for (int mt = 0; mt < 4; ++mt){
    #pragma unroll
    for (int nt = 0; nt < 4; ++nt){
      const int col = n0 + wc*64 + nt*16 + lr;
      #pragma unroll
      for (int r = 0; r < 4; ++r){
        const int row = m0 + wr*64 + mt*16 + 4*g + r;   // C/D: col=lane&15, row=(lane>>4)*4+r (m89)
        if (F32OUT) ((float*)Cp)[(size_t)row*N + col] = acc[mt][nt][r] * oscale;
        else ((unsigned short*)Cp)[(size_t)row*N + col] = f2bf(acc[mt][nt][r] * oscale);
      }
    }
  }
}

// ---------------- causal flash attention ----------------
// Grid: 1024 linear blocks; decode L -> (xcd=L&7, bh=xcd*8+(idx>>4), qblk=15-(idx&15))
// so each XCD owns 8 bh values (K/V L2-resident) and heavy q-blocks launch first.
// Block: 8 waves x 512 thr; QBLK=128 (wave w owns q-rows q0+w*16..+15), KVBLK=64.
// Swapped QK^T: S^T = mfma(K_frag, Q_frag) -> lane holds S[q=lane&15][kv=16kc+4g+r].
// Q pre-scaled by 1/sqrt(dk) in the Q-projection GEMM.
// PV: O^T = V^T @ P^T via mfma_16x16x16bf16_1k; V^T pre-transposed by GEMM
// (Vt[n][t]); both K and V staged via swizzled global_load_lds, double-buffered,
// prefetch issued before compute, one barrier (vmcnt drain) per tile.
__global__ __launch_bounds__(512) void attn_kernel(const unsigned short* __restrict__ Qg,
                                                   const unsigned short* __restrict__ Kg,
                                                   const unsigned short* __restrict__ Vt,
                                                   unsigned short* __restrict__ Og)
{
  __shared__ __attribute__((aligned(16))) unsigned short k_lds[2][64*64];
  __shared__ __attribute__((aligned(16))) unsigned short v_lds[2][64*64];
  const int tid = threadIdx.x;
  const int w = tid >> 6, l = tid & 63;
  const int g = l >> 4, lr = l & 15;
  const int L = blockIdx.x;
  const int xcd = L & 7, idx = L >> 3;
  const int bh = xcd*8 + (idx >> 4);
  const int qblk = 15 - (idx & 15);
  const int b = bh >> 4, h = bh & 15;
  const int q0 = qblk * 128;
  const int qlo = q0 + w*16;
  const int qhi = qlo + 15;
  const int qg = qlo + lr;                             // this lane's q row
  const size_t rowQ = (size_t)(b*T_SEQ + qg)*DM + h*DKH;
  bf16x8 qf[2];
  qf[0] = *(const bf16x8*)(Qg + rowQ + g*8);
  qf[1] = *(const bf16x8*)(Qg + rowQ + 32 + g*8);
  float m_run = NEG_INF, l_run = 0.f;
  f32x4 acc[4] = {};                                    // acc[mt]: O^T[dk=16mt+4g+r][q=lr]
  const int ntiles = 2*qblk + 2;
  const size_t baseK = (size_t)(b*T_SEQ)*DM + h*DKH;            // K rows [t][n]
  const size_t baseV = (size_t)(h*DKH)*MROWS + (size_t)b*T_SEQ; // Vt rows [n][t]

  // per-thread staging geometry (loop-invariant): 512 thr x 1 16B chunk each
  const int c0 = tid;                                   // 16B chunk id 0..511
  const int r0 = c0 >> 3, gc0 = (c0 & 7) ^ (r0 & 7);

  auto STAGE = [&](int jt, int buf){
    const int j0 = jt * 64;
    gload_lds16(Kg + baseK + (size_t)(j0 + r0)*DM + gc0*8, &k_lds[buf][c0*8]);
    gload_lds16(Vt + baseV + (size_t)r0*MROWS + j0 + gc0*8, &v_lds[buf][c0*8]);
  };

  STAGE(0, 0);
  __syncthreads();                                      // drains vmcnt -> buf0 ready

  for (int jt = 0; jt < ntiles; ++jt){
    const int cur = jt & 1;
    if (jt + 1 < ntiles) STAGE(jt + 1, cur ^ 1);        // prefetch next tile (hidden under compute)
    const int j0 = jt * 64;

    if (j0 <= qhi){                                     // skip fully-masked wave-tiles (wave-uniform)
      // QK^T (swapped): S^T tiles, kv=16 each
      f32x4 s[4];
      #pragma unroll
      for (int kc = 0; kc < 4; ++kc){
        f32x4 z = {};
        #pragma unroll
        for (int c2 = 0; c2 < 2; ++c2){
          int row = kc*16 + lr;
          int off = row*128 + ((c2*64 + g*16) ^ ((row & 7) << 4));
          bf16x8 kf = *(const bf16x8*)((const char*)k_lds[cur] + off);
          z = __builtin_amdgcn_mfma_f32_16x16x32_bf16(kf, qf[c2], z, 0, 0, 0);
        }
        s[kc] = z;
      }
      // causal mask (diagonal tiles only; wave-uniform branch) + tile max
      float p[4][4];
      float tm = NEG_INF;
      if (j0 + 63 <= qlo){                              // fully unmasked
        #pragma unroll
        for (int kc = 0; kc < 4; ++kc)
          #pragma unroll
          for (int r = 0; r < 4; ++r){
            p[kc][r] = s[kc][r];
            tm = fmaxf(tm, s[kc][r]);
          }
      } else {
        #pragma unroll
        for (int kc = 0; kc < 4; ++kc)
          #pragma unroll
          for (int r = 0; r < 4; ++r){
            int kvg = j0 + kc*16 + 4*g + r;
            float v = (kvg <= qg) ? s[kc][r] : NEG_INF;
            p[kc][r] = v;
            tm = fmaxf(tm, v);
          }
      }
      tm = fmaxf(tm, __shfl_xor(tm, 16));
      tm = fmaxf(tm, __shfl_xor(tm, 32));
      const float m_new = fmaxf(m_run, tm);
      const float fac = __expf(m_run - m_new);          // first tile: exp(-inf)=0
      float ps = 0.f;
      #pragma unroll
      for (int kc = 0; kc < 4; ++kc)
        #pragma unroll
        for (int r = 0; r < 4; ++r){
          float e = __expf(p[kc][r] - m_new);
          p[kc][r] = e;
          ps += e;
        }
      ps += __shfl_xor(ps, 16);
      ps += __shfl_xor(ps, 32);
      l_run = l_run * fac + ps;
      m_run = m_new;
      #pragma unroll
      for (int mt = 0; mt < 4; ++mt){
        acc[mt][0] *= fac; acc[mt][1] *= fac; acc[mt][2] *= fac; acc[mt][3] *= fac;
      }
      // pack P^T fragments (B-operand of 16x16x16: B[k=4g+i][n=lr] = p[kc][i] -- direct)
      bf16x4 pb[4];
      #pragma unroll
      for (int kc = 0; kc < 4; ++kc){
        bf16x4 t;
        t[0] = (short)f2bf(p[kc][0]); t[1] = (short)f2bf(p[kc][1]);
        t[2] = (short)f2bf(p[kc][2]); t[3] = (short)f2bf(p[kc][3]);
        pb[kc] = t;
      }
      // PV: A-frag = V^T[dk=mt*16+lr][kv=kc*16+4g..+3], swizzled 8B read from v_lds
      #pragma unroll
      for (int mt = 0; mt < 4; ++mt){
        const int vrow = mt*16 + lr;
        #pragma unroll
        for (int kc = 0; kc < 4; ++kc){
          const int voff = vrow*128 + ((((kc<<1) + (g>>1)) ^ (vrow & 7)) << 4) + ((g & 1) << 3);
          bf16x4 vf = *(const bf16x4*)((const char*)v_lds[cur] + voff);
          acc[mt] = __builtin_amdgcn_mfma_f32_16x16x16bf16_1k(vf, pb[kc], acc[mt], 0, 0, 0);
        }
      }
    }
    __syncthreads();                                    // all waves done with buf[cur]; prefetch drained
  }
  // epilogue: normalize, pack pairs, store bf16
  const float inv = 1.f / l_run;
  const size_t rowO = (size_t)(b*T_SEQ + qg)*DM + h*DKH;
  #pragma unroll
  for (int mt = 0; mt < 4; ++mt){
    unsigned u0 = (unsigned)f2bf(acc[mt][0]*inv) | ((unsigned)f2bf(acc[mt][1]*inv) << 16);
    unsigned u1 = (unsigned)f2bf(acc[mt][2]*inv) | ((unsigned)f2bf(acc[mt][3]*inv) << 16);
    *(unsigned*)(Og + rowO + mt*16 + 4*g)     = u0;
    *(unsigned*)(Og + rowO + mt*16 + 4*g + 2) = u1;
  }
}

// ---------------- launch ----------------
extern "C" void kernel_launch(void* const* d_in, const int* in_sizes, int n_in,
                              void* d_out, int out_size, void* d_ws, size_t ws_size,
                              hipStream_t stream)
{
  (void)in_sizes; (void)n_in; (void)out_size; (void)ws_size;
  const float* H  = (const float*)d_in[0];
  const float* Wq = (const float*)d_in[1];
  const float* Wk = (const float*)d_in[2];
  const float* Wv = (const float*)d_in[3];
  const float* Wo = (const float*)d_in[4];
  char* ws = (char*)d_ws;
  // ws layout (bytes): Hb 16MB | Wq/Wk/Wv/Wo^T bf16 2MB each | Q,K 16MB each | Vt 16MB | Ab 16MB = 88MB
  unsigned short* Hb  = (unsigned short*)(ws);
  unsigned short* Wqt = (unsigned short*)(ws + 16777216);
  unsigned short* Wkt = (unsigned short*)(ws + 18874368);
  unsigned short* Wvt = (unsigned short*)(ws + 20971520);
  unsigned short* Wot = (unsigned short*)(ws + 23068672);
  unsigned short* Qb  = (unsigned short*)(ws + 25165824);
  unsigned short* Kb  = (unsigned short*)(ws + 41943040);
  unsigned short* Vtb = (unsigned short*)(ws + 58720256);
  unsigned short* Ab  = (unsigned short*)(ws + 75497472);

  convh<<<2048, 256, 0, stream>>>((const float4*)H, (u16x4*)Hb, MROWS*DM/4);
  convw<<<dim3(32,32,4), dim3(32,8), 0, stream>>>(Wq, Wk, Wv, Wo, Wqt, Wkt, Wvt, Wot);
  gemm_bt<false><<<dim3(64,8), 256, 0, stream>>>(Hb, Wqt, Qb, MROWS, DM, DM, 0.125f); // Q pre-scaled 1/sqrt(64)
  gemm_bt<false><<<dim3(64,8), 256, 0, stream>>>(Hb, Wkt, Kb, MROWS, DM, DM, 1.0f);
  // V^T = (H Wv)^T computed directly: C[n][t] = sum_k Wvt[n][k] * Hb[t][k]
  gemm_bt<false><<<dim3(8,64), 256, 0, stream>>>(Wvt, Hb, Vtb, DM, MROWS, DM, 1.0f);
  attn_kernel<<<dim3(1024), 512, 0, stream>>>(Qb, Kb, Vtb, Ab);
  gemm_bt<true><<<dim3(64,8), 256, 0, stream>>>(Ab, Wot, d_out, MROWS, DM, DM, 1.0f);
}